// Round 13
// baseline (2563.161 us; speedup 1.0000x reference)
//
#include <hip/hip_runtime.h>
#include <hip/hip_bf16.h>
#include <cstdint>

#define LEAKV 0.2f
static const int Bb = 4, Nn = 4096, Mm = 16384, Kk = 20;
static const int Gg = 4;

typedef __attribute__((ext_vector_type(8))) short bf16x8;
typedef __attribute__((ext_vector_type(4))) float f32x4;
typedef unsigned long long u64;

__device__ __forceinline__ float lrelu_f(float v){ return v > 0.f ? v : LEAKV*v; }

// ---------------- workspace layout (float offsets, compile-time) ----------------
constexpr size_t O_DFLAG = 0;
constexpr size_t O_XYZ   = 16;
constexpr size_t O_NRM   = 49168;
constexpr size_t O_IDX   = 65552;
constexpr size_t O_GLOB  = 393232;
constexpr size_t O_GV    = 397328;
constexpr size_t O_S1 = 398352, O_B1 = 398416, O_S2 = 398480, O_B2 = 398544;
constexpr size_t O_S3 = 398608, O_B3 = 398736, O_S4 = 398864, O_B4 = 399120;
constexpr size_t O_SF = 399376, O_BF = 399888, O_SE = 400400, O_BE = 401424;
constexpr size_t O_SH1 = 402448, O_BH1 = 402704, O_SH2 = 402960, O_BH2 = 403216;
constexpr size_t O_BH3 = 403472;
constexpr size_t O_WCAT1 = 403536;
constexpr size_t O_WBH  = 404992;
constexpr size_t O_WBL  = 1033984;
constexpr size_t O_WCATH = 1662976;
constexpr size_t O_WCATL = 1695744;
constexpr size_t O_XCATH = 1728512;
constexpr size_t O_XCATL = 5922816;
constexpr size_t O_REGB  = 10117120;
constexpr size_t O_H1H = O_XCATH;
constexpr size_t O_H1L = O_XCATH + 2097152;
constexpr size_t O_H2H = O_XCATH + 4194304;
constexpr size_t O_H2L = O_XCATH + 6291456;
constexpr size_t WOF_WF = 0, WOF_WE = 262144, WOF_WH1 = 786432, WOF_WH2 = 1179648, WOF_WH3 = 1245184;
constexpr int WTOT = 1257984;

// ---------- register-resident top-20 list (used only in final_merge) ----------
#define REP20(X) X(0) X(1) X(2) X(3) X(4) X(5) X(6) X(7) X(8) X(9) X(10) X(11) X(12) X(13) X(14) X(15) X(16) X(17) X(18) X(19)
#define REP19(X) X(0,1) X(1,2) X(2,3) X(3,4) X(4,5) X(5,6) X(6,7) X(7,8) X(8,9) X(9,10) X(10,11) X(11,12) X(12,13) X(13,14) X(14,15) X(15,16) X(16,17) X(17,18) X(18,19)
struct KList {
#define KDECL(i) u64 k##i;
  REP20(KDECL)
#undef KDECL
  __device__ __forceinline__ void init(){
#define KINIT(i) k##i = ~0ULL;
    REP20(KINIT)
#undef KINIT
  }
  __device__ __forceinline__ void insert(u64 key){
    k0 = key;
#define KSWAP(a,b) { bool s_ = k##a < k##b; u64 mx_ = s_ ? k##b : k##a; u64 mn_ = s_ ? k##a : k##b; k##a = mx_; k##b = mn_; }
    REP19(KSWAP)
#undef KSWAP
  }
};

// ---------- dtype detector ----------
__global__ void detect_kernel(const void* __restrict__ xyz, int n, int* __restrict__ flag){
  __shared__ int cnt;
  if (threadIdx.x == 0) cnt = 0;
  __syncthreads();
  const __hip_bfloat16* p = (const __hip_bfloat16*)xyz;
  int local = 0;
  for (int i = threadIdx.x; i < n; i += 256){
    float v = __bfloat162float(p[i]);
    if (!(fabsf(v) < 1000.f)) local++;
  }
  atomicAdd(&cnt, local);
  __syncthreads();
  if (threadIdx.x == 0) *flag = (cnt < n/16) ? 1 : 0;   // 1 = bf16, 0 = fp32
}

__device__ __forceinline__ float rdval(const void* p, int i, int flag){
  return flag ? __bfloat162float(((const __hip_bfloat16*)p)[i]) : ((const float*)p)[i];
}

// ---------- fused small-input conversion + glob init ----------
__global__ void cvt_small_kernel(float* __restrict__ ws, const int* __restrict__ flag,
    const void* xyz, const void* s1, const void* b1, const void* s2, const void* b2,
    const void* s3, const void* b3, const void* s4, const void* b4,
    const void* sf, const void* bf, const void* se, const void* be,
    const void* sh1, const void* bh1, const void* sh2, const void* bh2, const void* bh3)
{
  int t = blockIdx.x*256 + threadIdx.x;
  int fl = *flag;
  if (t < 49152){ ws[O_XYZ + t] = rdval(xyz, t, fl); return; }
  t -= 49152;
  if (t < 4096){ ((unsigned*)(ws + O_GLOB))[t] = 0u; return; }
  t -= 4096;
  if (t < 64){ ws[O_S1+t] = rdval(s1,t,fl); return; }  t -= 64;
  if (t < 64){ ws[O_B1+t] = rdval(b1,t,fl); return; }  t -= 64;
  if (t < 64){ ws[O_S2+t] = rdval(s2,t,fl); return; }  t -= 64;
  if (t < 64){ ws[O_B2+t] = rdval(b2,t,fl); return; }  t -= 64;
  if (t < 128){ ws[O_S3+t] = rdval(s3,t,fl); return; } t -= 128;
  if (t < 128){ ws[O_B3+t] = rdval(b3,t,fl); return; } t -= 128;
  if (t < 256){ ws[O_S4+t] = rdval(s4,t,fl); return; } t -= 256;
  if (t < 256){ ws[O_B4+t] = rdval(b4,t,fl); return; } t -= 256;
  if (t < 512){ ws[O_SF+t] = rdval(sf,t,fl); return; } t -= 512;
  if (t < 512){ ws[O_BF+t] = rdval(bf,t,fl); return; } t -= 512;
  if (t < 1024){ ws[O_SE+t] = rdval(se,t,fl); return; } t -= 1024;
  if (t < 1024){ ws[O_BE+t] = rdval(be,t,fl); return; } t -= 1024;
  if (t < 256){ ws[O_SH1+t] = rdval(sh1,t,fl); return; } t -= 256;
  if (t < 256){ ws[O_BH1+t] = rdval(bh1,t,fl); return; } t -= 256;
  if (t < 256){ ws[O_SH2+t] = rdval(sh2,t,fl); return; } t -= 256;
  if (t < 256){ ws[O_BH2+t] = rdval(bh2,t,fl); return; } t -= 256;
  if (t < 50){ ws[O_BH3+t] = rdval(bh3,t,fl); return; }
}

// ---------- fused big-weight conversion -> bf16 hi/lo ----------
__global__ void cvt_w_kernel(float* __restrict__ ws, const int* __restrict__ flag,
    const void* wf, const void* we, const void* wh1, const void* wh2, const void* wh3)
{
  int t = blockIdx.x*256 + threadIdx.x;
  if (t >= WTOT) return;
  int fl = *flag;
  float v;
  if (t < (int)WOF_WE)        v = rdval(wf,  t, fl);
  else if (t < (int)WOF_WH1)  v = rdval(we,  t - WOF_WE, fl);
  else if (t < (int)WOF_WH2)  v = rdval(wh1, t - WOF_WH1, fl);
  else if (t < (int)WOF_WH3)  v = rdval(wh2, t - WOF_WH2, fl);
  else                        v = rdval(wh3, t - WOF_WH3, fl);
  __hip_bfloat16 h = __float2bfloat16(v);
  ((__hip_bfloat16*)(ws + O_WBH))[t] = h;
  ((__hip_bfloat16*)(ws + O_WBL))[t] = __float2bfloat16(v - __bfloat162float(h));
}

// ---------- edgeconv weight prep: wcat = [w_d ; w_x - w_d] -> bf16 h/l ----------
__global__ void prep_w_hl_kernel(float* __restrict__ ws, const int* __restrict__ flag,
                                 const void* __restrict__ w, int C, int O){
  int t = blockIdx.x*256 + threadIdx.x;
  if (t >= O*C) return;
  int fl = *flag;
  int o = t / C, c = t - o*C;
  float wd = rdval(w, o*2*C + c, fl);
  float wx = rdval(w, o*2*C + C + c, fl);
  float dx = wx - wd;
  __hip_bfloat16* Wh = (__hip_bfloat16*)(ws + O_WCATH);
  __hip_bfloat16* Wl = (__hip_bfloat16*)(ws + O_WCATL);
  __hip_bfloat16 h1 = __float2bfloat16(wd);
  Wh[o*C + c] = h1; Wl[o*C + c] = __float2bfloat16(wd - __bfloat162float(h1));
  __hip_bfloat16 h2 = __float2bfloat16(dx);
  Wh[(O+o)*C + c] = h2; Wl[(O+o)*C + c] = __float2bfloat16(dx - __bfloat162float(h2));
}

// layer-1 fp32 wcat [128][3]
__global__ void prep_w1_kernel(float* __restrict__ ws, const int* __restrict__ flag,
                               const void* __restrict__ w){
  int t = blockIdx.x*256 + threadIdx.x;
  if (t >= 64*3) return;
  int fl = *flag;
  int o = t / 3, c = t - o*3;
  float wd = rdval(w, o*6 + c, fl);
  float wx = rdval(w, o*6 + 3 + c, fl);
  ws[O_WCAT1 + o*3 + c] = wd;
  ws[O_WCAT1 + (64+o)*3 + c] = wx - wd;
}

// ---------- norms ----------
__global__ void norms_kernel(const float* __restrict__ x, int ld, int C, float* __restrict__ out){
  int t = blockIdx.x*256 + threadIdx.x;
  if (t >= Mm) return;
  const float* r = x + (size_t)t*ld;
  float s = 0.f;
  for (int c = 0; c < C; ++c){ float v = r[c]; s += v*v; }
  out[t] = s;
}
__global__ void norms_hl_kernel(const __hip_bfloat16* __restrict__ Xh, const __hip_bfloat16* __restrict__ Xl,
                                int ld, int C, float* __restrict__ out){
  int t = blockIdx.x*256 + threadIdx.x;
  if (t >= Mm) return;
  size_t base = (size_t)t*ld;
  float s = 0.f;
  for (int c = 0; c < C; ++c){
    float v = __bfloat162float(Xh[base+c]) + __bfloat162float(Xl[base+c]);
    s += v*v;
  }
  out[t] = s;
}

__device__ __forceinline__ unsigned fkey(float f){
  unsigned u = __float_as_uint(f);
  return (u & 0x80000000u) ? ~u : (u | 0x80000000u);
}
__device__ __forceinline__ float funkey(unsigned k){
  if (k == 0u) return -1e30f;
  unsigned u = (k & 0x80000000u) ? (k ^ 0x80000000u) : ~k;
  return __uint_as_float(u);
}

// distributed ascending top-20 across lanes 0..19 (1 u64/lane -> cannot spill).
// insert kk (uniform value, kk < current lane-19 threshold):
__device__ __forceinline__ u64 dlist_insert(u64 lst, u64 kk, int lane){
  u64 up = __shfl_up(lst, 1, 64);
  bool cs = lst > kk;
  bool cp = (lane > 0) && (up > kk);
  return cs ? (cp ? up : kk) : lst;
}

// ---------- MFMA KNN: wave owns 16 queries; distributed per-lane selection ----------
template<int C>
__global__ __launch_bounds__(256, 4) void knn_mfma_kernel(
    const __hip_bfloat16* __restrict__ Xh, const __hip_bfloat16* __restrict__ Xl, int lda,
    const float* __restrict__ n2,
    u64* __restrict__ kpart)
{
  constexpr int KS = C/32;
  __shared__ float dist[4][16*66];      // per-wave slab, row stride 66 (bank-spread)
  const int lane = threadIdx.x & 63;
  const int wv = threadIdx.x >> 6;
  const int b = blockIdx.z, bN = b*Nn;
  const int q0 = blockIdx.x*64 + wv*16;
  const int g = blockIdx.y;             // 0..Gg-1
  const int kq = (lane >> 4) * 8;
  float* dw = dist[wv];

  bf16x8 Ah[KS], Al[KS];
  {
    const size_t qrow = (size_t)(bN + q0 + (lane & 15))*lda;
    #pragma unroll
    for (int s = 0; s < KS; ++s){
      Ah[s] = *reinterpret_cast<const bf16x8*>(Xh + qrow + s*32 + kq);
      Al[s] = *reinterpret_cast<const bf16x8*>(Xl + qrow + s*32 + kq);
    }
  }

  u64 lst[16];
  #pragma unroll
  for (int q = 0; q < 16; ++q) lst[q] = ~0ULL;

  const int base = g*(Nn/Gg);
  for (int grp = 0; grp < (Nn/Gg)/64; ++grp){
    const int c0 = base + grp*64;
    // 4 MFMA tiles -> dist[16 queries][64 candidates]
    #pragma unroll
    for (int tt = 0; tt < 4; ++tt){
      const int j0 = c0 + tt*16;
      const size_t crow = (size_t)(bN + j0 + (lane & 15))*lda;
      f32x4 acc = {0.f, 0.f, 0.f, 0.f};
      #pragma unroll
      for (int s = 0; s < KS; ++s){
        bf16x8 Bh = *reinterpret_cast<const bf16x8*>(Xh + crow + s*32 + kq);
        bf16x8 Bl = *reinterpret_cast<const bf16x8*>(Xl + crow + s*32 + kq);
        acc = __builtin_amdgcn_mfma_f32_16x16x32_bf16(Ah[s], Bh, acc, 0, 0, 0);
        acc = __builtin_amdgcn_mfma_f32_16x16x32_bf16(Ah[s], Bl, acc, 0, 0, 0);
        acc = __builtin_amdgcn_mfma_f32_16x16x32_bf16(Al[s], Bh, acc, 0, 0, 0);
      }
      float nj = n2[bN + j0 + (lane & 15)];
      const int rbase = (lane >> 4)*4;
      #pragma unroll
      for (int r = 0; r < 4; ++r)
        dw[(rbase + r)*66 + tt*16 + (lane & 15)] = nj - 2.f*acc[r];
    }
    // selection: lanes <-> 64 candidates, per query
    #pragma unroll
    for (int q = 0; q < 16; ++q){
      float d = dw[q*66 + lane];
      u64 key = ((u64)fkey(d) << 32) | (unsigned)(c0 + lane);
      u64 thr = __shfl(lst[q], 19, 64);
      u64 bal = __ballot(key < thr);
      while (bal){
        int src = (int)__ffsll((unsigned long long)bal) - 1;
        bal &= bal - 1;
        u64 kk = __shfl(key, src, 64);
        if (kk < thr){
          lst[q] = dlist_insert(lst[q], kk, lane);
          thr = __shfl(lst[q], 19, 64);
        }
      }
    }
  }
  // output ascending lists
  #pragma unroll
  for (int q = 0; q < 16; ++q){
    if (lane < 20)
      kpart[((size_t)(bN + q0 + q)*Gg + g)*20 + lane] = lst[q];
  }
}

// ---------- KNN for C=3: one query per wave, distributed selection, writes idx ----------
__global__ __launch_bounds__(256) void knn3_kernel(
    const float* __restrict__ x, const float* __restrict__ n2, int* __restrict__ idx)
{
  const int lane = threadIdx.x & 63;
  const int wv = threadIdx.x >> 6;
  const int q = blockIdx.x*4 + wv;          // 0..Mm-1
  const int b = q >> 12;                    // q / Nn
  const int bN = b*Nn;
  const int qi = q & (Nn-1);
  const float* qp = x + (size_t)(bN + qi)*3;
  float qx = qp[0], qy = qp[1], qz = qp[2];
  u64 lst = ~0ULL;
  u64 thr = ~0ULL;
  for (int s = 0; s < Nn/64; ++s){
    int j = s*64 + lane;
    const float* cp = x + (size_t)(bN + j)*3;
    float d = n2[bN + j] - 2.f*(qx*cp[0] + qy*cp[1] + qz*cp[2]);
    u64 key = ((u64)fkey(d) << 32) | (unsigned)j;
    u64 bal = __ballot(key < thr);
    while (bal){
      int src = (int)__ffsll((unsigned long long)bal) - 1;
      bal &= bal - 1;
      u64 kk = __shfl(key, src, 64);
      if (kk < thr){
        lst = dlist_insert(lst, kk, lane);
        thr = __shfl(lst, 19, 64);
      }
    }
  }
  if (lane < 20) idx[(size_t)q*Kk + lane] = (int)(lst & 0xffffffffu);
}

// ---------- final merge: Gg sorted ascending 20-lists -> top-20 ----------
__global__ __launch_bounds__(256, 4) void knn_final_merge_kernel(
    const u64* __restrict__ kpart, int* __restrict__ idx)
{
  int t = blockIdx.x*256 + threadIdx.x;
  if (t >= Mm) return;
  const u64* base = kpart + (size_t)t*Gg*20;
  KList kl; kl.init();
  for (int g = 0; g < Gg; ++g){
    const u64* lp = base + g*20;
    #pragma unroll 1
    for (int l = 0; l < 20; ++l){
      u64 key = lp[l];
      if (key >= kl.k0) break;
      kl.insert(key);
    }
  }
#define KOUTI(i) idx[(size_t)t*Kk + (19-(i))] = (int)(kl.k##i & 0xffffffffu);
  REP20(KOUTI)
#undef KOUTI
}

// ---------- gather-max epilogue: fp32 tb -> bf16 h/l activations ----------
__global__ void gathermax_kernel(const float* __restrict__ tb, const int* __restrict__ idx,
                                 const float* __restrict__ sv, const float* __restrict__ bv,
                                 int O, __hip_bfloat16* __restrict__ outh,
                                 __hip_bfloat16* __restrict__ outl, int ldo)
{
  int t = blockIdx.x*256 + threadIdx.x;
  int o = t % O;
  int m = t / O;           // b*N + i
  int b = m / Nn;
  const int twoO = 2*O;
  const int* ip = idx + (size_t)m*Kk;
  float mx = -1e30f;
  for (int j = 0; j < Kk; ++j){
    int jj = ip[j] & (Nn-1);
    mx = fmaxf(mx, tb[(size_t)(b*Nn + jj)*twoO + o]);
  }
  float basev = tb[(size_t)m*twoO + O + o];
  float y = lrelu_f((mx + basev) * sv[o] + bv[o]);
  __hip_bfloat16 h = __float2bfloat16(y);
  outh[(size_t)m*ldo + o] = h;
  outl[(size_t)m*ldo + o] = __float2bfloat16(y - __bfloat162float(h));
}

// ---------- MFMA GEMM (LDS-staged): C[M,O] = (Ah+Al)[M,K] @ (Wh+Wl)[O,K]^T ----------
__global__ __launch_bounds__(256) void mfma_gemm_kernel(
    const __hip_bfloat16* __restrict__ Ah, const __hip_bfloat16* __restrict__ Al, int lda,
    const __hip_bfloat16* __restrict__ Wh, const __hip_bfloat16* __restrict__ Wl, int ldw,
    float* __restrict__ Cf, __hip_bfloat16* __restrict__ Ch, __hip_bfloat16* __restrict__ Cl, int ldc,
    int K, int O,
    const float* __restrict__ scale, const float* __restrict__ bias,
    const float* __restrict__ addvec, int lrelu_flag,
    unsigned* __restrict__ pool)
{
  constexpr int LDK = 40;
  __shared__ __align__(16) __hip_bfloat16 AsH[128*LDK];
  __shared__ __align__(16) __hip_bfloat16 AsL[128*LDK];
  __shared__ __align__(16) __hip_bfloat16 BsH[128*LDK];
  __shared__ __align__(16) __hip_bfloat16 BsL[128*LDK];
  __shared__ float redp[2][128];
  const int tid = threadIdx.x;
  const int lane = tid & 63, w = tid >> 6;
  const int o0 = blockIdx.x*128, m0 = blockIdx.y*128;
  const int wr = (w >> 1)*64, wc = (w & 1)*64;
  const int kq = (lane >> 4)*8;
  const int fr = lane & 15;
  f32x4 acc[4][4] = {};

  for (int k0 = 0; k0 < K; k0 += 32){
    __syncthreads();
    #pragma unroll
    for (int j = 0; j < 2; ++j){
      int chunk = tid + j*256;
      int r = chunk >> 2, k8 = (chunk & 3)*8;
      size_t ga = (size_t)(m0 + r)*lda + k0 + k8;
      int oo = o0 + r; if (oo >= O) oo = O - 1;
      size_t gb = (size_t)oo*ldw + k0 + k8;
      int ls = r*LDK + k8;
      *reinterpret_cast<bf16x8*>(&AsH[ls]) = *reinterpret_cast<const bf16x8*>(Ah + ga);
      *reinterpret_cast<bf16x8*>(&AsL[ls]) = *reinterpret_cast<const bf16x8*>(Al + ga);
      *reinterpret_cast<bf16x8*>(&BsH[ls]) = *reinterpret_cast<const bf16x8*>(Wh + gb);
      *reinterpret_cast<bf16x8*>(&BsL[ls]) = *reinterpret_cast<const bf16x8*>(Wl + gb);
    }
    __syncthreads();
    bf16x8 ah[4], al[4];
    #pragma unroll
    for (int mi = 0; mi < 4; ++mi){
      int ls = (wr + mi*16 + fr)*LDK + kq;
      ah[mi] = *reinterpret_cast<const bf16x8*>(&AsH[ls]);
      al[mi] = *reinterpret_cast<const bf16x8*>(&AsL[ls]);
    }
    #pragma unroll
    for (int ni = 0; ni < 4; ++ni){
      int ls = (wc + ni*16 + fr)*LDK + kq;
      bf16x8 bh = *reinterpret_cast<const bf16x8*>(&BsH[ls]);
      bf16x8 bl = *reinterpret_cast<const bf16x8*>(&BsL[ls]);
      #pragma unroll
      for (int mi = 0; mi < 4; ++mi){
        acc[mi][ni] = __builtin_amdgcn_mfma_f32_16x16x32_bf16(ah[mi], bh, acc[mi][ni], 0, 0, 0);
        acc[mi][ni] = __builtin_amdgcn_mfma_f32_16x16x32_bf16(ah[mi], bl, acc[mi][ni], 0, 0, 0);
        acc[mi][ni] = __builtin_amdgcn_mfma_f32_16x16x32_bf16(al[mi], bh, acc[mi][ni], 0, 0, 0);
      }
    }
  }
  const int b = m0 / Nn;
  if (pool){
    #pragma unroll
    for (int ni = 0; ni < 4; ++ni){
      int o = o0 + wc + ni*16 + fr;
      float sc_ = scale[o], bi_ = bias[o];
      float m = -1e30f;
      #pragma unroll
      for (int mi = 0; mi < 4; ++mi)
        #pragma unroll
        for (int r = 0; r < 4; ++r)
          m = fmaxf(m, lrelu_f(acc[mi][ni][r]*sc_ + bi_));
      m = fmaxf(m, __shfl_xor(m, 16, 64));
      m = fmaxf(m, __shfl_xor(m, 32, 64));
      if ((lane >> 4) == 0) redp[w >> 1][wc + ni*16 + fr] = m;
    }
    __syncthreads();
    if (tid < 128){
      float m = fmaxf(redp[0][tid], redp[1][tid]);
      atomicMax(&pool[b*O + o0 + tid], fkey(m));
    }
    return;
  }
  #pragma unroll
  for (int ni = 0; ni < 4; ++ni){
    int o = o0 + wc + ni*16 + fr;
    if (o >= O) continue;
    float sc_ = scale ? scale[o] : 1.f;
    float bi_ = bias ? bias[o] : 0.f;
    float av  = addvec ? addvec[b*O + o] : 0.f;
    #pragma unroll
    for (int mi = 0; mi < 4; ++mi){
      #pragma unroll
      for (int r = 0; r < 4; ++r){
        int m = m0 + wr + mi*16 + (lane >> 4)*4 + r;
        float y = acc[mi][ni][r] + av;
        if (scale) y = y*sc_ + bi_;
        else       y = y + bi_;
        if (lrelu_flag) y = lrelu_f(y);
        if (Ch){
          __hip_bfloat16 h = __float2bfloat16(y);
          Ch[(size_t)m*ldc + o] = h;
          Cl[(size_t)m*ldc + o] = __float2bfloat16(y - __bfloat162float(h));
        } else {
          Cf[(size_t)m*ldc + o] = y;
        }
      }
    }
  }
}

// ---------- fp32 GEMM (layer-1 tb only, K=3) ----------
__global__ __launch_bounds__(256) void gemm_kernel(
    const float* __restrict__ A, int lda,
    const float* __restrict__ W, int ldw,
    float* __restrict__ Cf, int ldc, int K, int O)
{
  const int tid = threadIdx.x;
  const int tx = tid & 15, ty = tid >> 4;
  const int m0 = blockIdx.y * 64;
  const int o0 = blockIdx.x * 64;
  __shared__ __align__(16) float As[16*68];
  __shared__ __align__(16) float Ws[16*68];
  float acc[4][4] = {};
  for (int k0 = 0; k0 < K; k0 += 16){
    __syncthreads();
    #pragma unroll
    for (int r = 0; r < 4; ++r){
      int e = tid + r*256;
      int k = e & 15, mi = e >> 4;
      int kk = k0 + k;
      float v = 0.f, wv = 0.f;
      if (kk < K) v = A[(size_t)(m0+mi)*lda + kk];
      int oo = o0 + mi;
      if (kk < K && oo < O) wv = W[(size_t)oo*ldw + kk];
      As[k*68 + mi] = v;
      Ws[k*68 + mi] = wv;
    }
    __syncthreads();
    #pragma unroll
    for (int kk = 0; kk < 16; ++kk){
      float4 av = *reinterpret_cast<const float4*>(&As[kk*68 + ty*4]);
      float4 wv = *reinterpret_cast<const float4*>(&Ws[kk*68 + tx*4]);
      float a4[4] = {av.x, av.y, av.z, av.w};
      float w4[4] = {wv.x, wv.y, wv.z, wv.w};
      #pragma unroll
      for (int i = 0; i < 4; ++i)
        #pragma unroll
        for (int j = 0; j < 4; ++j)
          acc[i][j] += a4[i]*w4[j];
    }
  }
  #pragma unroll
  for (int i = 0; i < 4; ++i){
    int m = m0 + ty*4 + i;
    #pragma unroll
    for (int j = 0; j < 4; ++j){
      int o = o0 + tx*4 + j;
      if (o >= O) continue;
      Cf[(size_t)m*ldc + o] = acc[i][j];
    }
  }
}

// gvec[b,o2] = sum_c wh1[o2, 512+c] * glob[b,c]
__global__ void gvec_kernel(const __hip_bfloat16* __restrict__ Wh, const __hip_bfloat16* __restrict__ Wl,
                            const unsigned* __restrict__ glob, float* __restrict__ gv){
  int lane = threadIdx.x & 63, w = threadIdx.x >> 6;
  int o2 = blockIdx.x*4 + w;
  int b = blockIdx.y;
  size_t base = (size_t)o2*1536 + 512;
  float s = 0.f;
  for (int c = lane; c < 1024; c += 64){
    float wv = __bfloat162float(Wh[base+c]) + __bfloat162float(Wl[base+c]);
    s += wv * funkey(glob[b*1024 + c]);
  }
  #pragma unroll
  for (int off = 32; off >= 1; off >>= 1) s += __shfl_xor(s, off, 64);
  if (lane == 0) gv[b*256 + o2] = s;
}

// ---------- flag-gated output store ----------
__global__ void store_out_kernel(const float* __restrict__ src, const int* __restrict__ flag,
                                 void* __restrict__ dst, int n){
  int t = blockIdx.x*256 + threadIdx.x;
  if (t >= n) return;
  float v = src[t];
  if (*flag) ((__hip_bfloat16*)dst)[t] = __float2bfloat16(v);
  else       ((float*)dst)[t] = v;
}

extern "C" void kernel_launch(void* const* d_in, const int* in_sizes, int n_in,
                              void* d_out, int out_size, void* d_ws, size_t ws_size,
                              hipStream_t stream) {
  (void)in_sizes; (void)n_in; (void)out_size; (void)ws_size;
  float* ws = (float*)d_ws;
  int* dflag = (int*)(ws + O_DFLAG);
  float* xyzf = ws + O_XYZ;
  float* nrm  = ws + O_NRM;
  int*   idx  = (int*)(ws + O_IDX);
  unsigned* glob = (unsigned*)(ws + O_GLOB);
  float* gv = ws + O_GV;
  __hip_bfloat16* WBH = (__hip_bfloat16*)(ws + O_WBH);
  __hip_bfloat16* WBL = (__hip_bfloat16*)(ws + O_WBL);
  __hip_bfloat16* WCH = (__hip_bfloat16*)(ws + O_WCATH);
  __hip_bfloat16* WCL = (__hip_bfloat16*)(ws + O_WCATL);
  __hip_bfloat16* XCH = (__hip_bfloat16*)(ws + O_XCATH);
  __hip_bfloat16* XCL = (__hip_bfloat16*)(ws + O_XCATL);
  float* regB = ws + O_REGB;
  u64*   kpart = (u64*)regB;                 // [M][4][20] u64 = 10.5MB
  float* tb    = regB;
  __hip_bfloat16* XLH = (__hip_bfloat16*)regB;
  __hip_bfloat16* XLL = (__hip_bfloat16*)(regB + 4194304);
  float* logitsF = regB;
  __hip_bfloat16* H1H = (__hip_bfloat16*)(ws + O_H1H);
  __hip_bfloat16* H1L = (__hip_bfloat16*)(ws + O_H1L);
  __hip_bfloat16* H2H = (__hip_bfloat16*)(ws + O_H2H);
  __hip_bfloat16* H2L = (__hip_bfloat16*)(ws + O_H2L);

  // ---- detect + fused conversions ----
  detect_kernel<<<1, 256, 0, stream>>>(d_in[0], Mm*3, dflag);
  cvt_small_kernel<<<(49152+4096+5200+255)/256, 256, 0, stream>>>(ws, dflag,
      d_in[0], d_in[3], d_in[4], d_in[6], d_in[7], d_in[9], d_in[10], d_in[12], d_in[13],
      d_in[15], d_in[16], d_in[18], d_in[19], d_in[21], d_in[22], d_in[24], d_in[25], d_in[27]);
  cvt_w_kernel<<<(WTOT+255)/256, 256, 0, stream>>>(ws, dflag,
      d_in[14], d_in[17], d_in[20], d_in[23], d_in[26]);

  auto mgemm = [&](const __hip_bfloat16* Ah, const __hip_bfloat16* Al, int lda,
                   const __hip_bfloat16* Wh, const __hip_bfloat16* Wl, int ldw,
                   float* Cf, __hip_bfloat16* Ch, __hip_bfloat16* Cl, int ldc,
                   int K, int O, const float* sc, const float* bi, const float* av,
                   int lr, unsigned* pool){
    dim3 g((O+127)/128, Mm/128);
    mfma_gemm_kernel<<<g, 256, 0, stream>>>(Ah, Al, lda, Wh, Wl, ldw, Cf, Ch, Cl, ldc,
                                            K, O, sc, bi, av, lr, pool);
  };

  // ---- edgeconv layer 1 (C=3): distributed-selection knn3 writes idx directly ----
  norms_kernel<<<Mm/256, 256, 0, stream>>>(xyzf, 3, 3, nrm);
  knn3_kernel<<<Mm/4, 256, 0, stream>>>(xyzf, nrm, idx);
  prep_w1_kernel<<<1, 256, 0, stream>>>(ws, dflag, d_in[2]);
  gemm_kernel<<<dim3(2, Mm/64), 256, 0, stream>>>(xyzf, 3, ws + O_WCAT1, 3, tb, 128, 3, 128);
  gathermax_kernel<<<((size_t)Mm*64)/256, 256, 0, stream>>>(
      tb, idx, ws+O_S1, ws+O_B1, 64, XCH + 0, XCL + 0, 512);

  // ---- edgeconv layers 2-4 (MFMA path) ----
  struct LayerDef { int coff; int C; int O; size_t so, bo; int win; };
  LayerDef L[3] = {
    {0,   64, 64,  O_S2, O_B2, 5},
    {64,  64, 128, O_S3, O_B3, 8},
    {128, 128, 256, O_S4, O_B4, 11},
  };
  for (int li = 0; li < 3; ++li){
    int C = L[li].C, O = L[li].O, coff = L[li].coff;
    norms_hl_kernel<<<Mm/256, 256, 0, stream>>>(XCH + coff, XCL + coff, 512, C, nrm);
    if (C == 64)
      knn_mfma_kernel<64><<<dim3(Nn/64, Gg, Bb), 256, 0, stream>>>(XCH + coff, XCL + coff, 512, nrm, kpart);
    else
      knn_mfma_kernel<128><<<dim3(Nn/64, Gg, Bb), 256, 0, stream>>>(XCH + coff, XCL + coff, 512, nrm, kpart);
    knn_final_merge_kernel<<<Mm/256, 256, 0, stream>>>(kpart, idx);
    prep_w_hl_kernel<<<(O*C+255)/256, 256, 0, stream>>>(ws, dflag, d_in[L[li].win], C, O);
    mgemm(XCH + coff, XCL + coff, 512, WCH, WCL, C, tb, nullptr, nullptr, 2*O, C, 2*O,
          nullptr, nullptr, nullptr, 0, nullptr);
    gathermax_kernel<<<((size_t)Mm*O)/256, 256, 0, stream>>>(
        tb, idx, ws + L[li].so, ws + L[li].bo, O, XCH + coff + C, XCL + coff + C, 512);
  }

  // ---- chain ----
  mgemm(XCH, XCL, 512, WBH + WOF_WF, WBL + WOF_WF, 512, nullptr, XLH, XLL, 512,
        512, 512, ws+O_SF, ws+O_BF, nullptr, 1, nullptr);
  mgemm(XLH, XLL, 512, WBH + WOF_WE, WBL + WOF_WE, 512, nullptr, nullptr, nullptr, 0,
        512, 1024, ws+O_SE, ws+O_BE, nullptr, 1, glob);
  gvec_kernel<<<dim3(64, Bb), 256, 0, stream>>>(WBH + WOF_WH1, WBL + WOF_WH1, glob, gv);
  mgemm(XLH, XLL, 512, WBH + WOF_WH1, WBL + WOF_WH1, 1536, nullptr, H1H, H1L, 256,
        512, 256, ws+O_SH1, ws+O_BH1, gv, 1, nullptr);
  mgemm(H1H, H1L, 256, WBH + WOF_WH2, WBL + WOF_WH2, 256, nullptr, H2H, H2L, 256,
        256, 256, ws+O_SH2, ws+O_BH2, nullptr, 1, nullptr);
  mgemm(H2H, H2L, 256, WBH + WOF_WH3, WBL + WOF_WH3, 256, logitsF, nullptr, nullptr, 50,
        256, 50, nullptr, ws+O_BH3, nullptr, 0, nullptr);
  store_out_kernel<<<((size_t)Mm*50 + 255)/256, 256, 0, stream>>>(logitsF, dflag, d_out, Mm*50);
}

// Round 14
// 1836.872 us; speedup vs baseline: 1.3954x; 1.3954x over previous
//
#include <hip/hip_runtime.h>
#include <hip/hip_bf16.h>
#include <cstdint>

#define LEAKV 0.2f
static const int Bb = 4, Nn = 4096, Mm = 16384, Kk = 20;
static const int Gg = 4;

typedef __attribute__((ext_vector_type(8))) short bf16x8;
typedef __attribute__((ext_vector_type(4))) float f32x4;
typedef unsigned long long u64;

__device__ __forceinline__ float lrelu_f(float v){ return v > 0.f ? v : LEAKV*v; }

// ---------------- workspace layout (float offsets, compile-time) ----------------
constexpr size_t O_DFLAG = 0;
constexpr size_t O_XYZ   = 16;
constexpr size_t O_NRM   = 49168;
constexpr size_t O_IDX   = 65552;
constexpr size_t O_GLOB  = 393232;
constexpr size_t O_GV    = 397328;
constexpr size_t O_S1 = 398352, O_B1 = 398416, O_S2 = 398480, O_B2 = 398544;
constexpr size_t O_S3 = 398608, O_B3 = 398736, O_S4 = 398864, O_B4 = 399120;
constexpr size_t O_SF = 399376, O_BF = 399888, O_SE = 400400, O_BE = 401424;
constexpr size_t O_SH1 = 402448, O_BH1 = 402704, O_SH2 = 402960, O_BH2 = 403216;
constexpr size_t O_BH3 = 403472;
constexpr size_t O_WCAT1 = 403536;
constexpr size_t O_WBH  = 404992;
constexpr size_t O_WBL  = 1033984;
constexpr size_t O_WCATH = 1662976;
constexpr size_t O_WCATL = 1695744;
constexpr size_t O_XCATH = 1728512;
constexpr size_t O_XCATL = 5922816;
constexpr size_t O_REGB  = 10117120;
constexpr size_t O_H1H = O_XCATH;
constexpr size_t O_H1L = O_XCATH + 2097152;
constexpr size_t O_H2H = O_XCATH + 4194304;
constexpr size_t O_H2L = O_XCATH + 6291456;
constexpr size_t WOF_WF = 0, WOF_WE = 262144, WOF_WH1 = 786432, WOF_WH2 = 1179648, WOF_WH3 = 1245184;
constexpr int WTOT = 1257984;

// ---------- register-resident top-20 list (used only in final_merge) ----------
#define REP20(X) X(0) X(1) X(2) X(3) X(4) X(5) X(6) X(7) X(8) X(9) X(10) X(11) X(12) X(13) X(14) X(15) X(16) X(17) X(18) X(19)
#define REP19(X) X(0,1) X(1,2) X(2,3) X(3,4) X(4,5) X(5,6) X(6,7) X(7,8) X(8,9) X(9,10) X(10,11) X(11,12) X(12,13) X(13,14) X(14,15) X(15,16) X(16,17) X(17,18) X(18,19)
struct KList {
#define KDECL(i) u64 k##i;
  REP20(KDECL)
#undef KDECL
  __device__ __forceinline__ void init(){
#define KINIT(i) k##i = ~0ULL;
    REP20(KINIT)
#undef KINIT
  }
  __device__ __forceinline__ void insert(u64 key){
    k0 = key;
#define KSWAP(a,b) { bool s_ = k##a < k##b; u64 mx_ = s_ ? k##b : k##a; u64 mn_ = s_ ? k##a : k##b; k##a = mx_; k##b = mn_; }
    REP19(KSWAP)
#undef KSWAP
  }
};

// ---------- dtype detector ----------
__global__ void detect_kernel(const void* __restrict__ xyz, int n, int* __restrict__ flag){
  __shared__ int cnt;
  if (threadIdx.x == 0) cnt = 0;
  __syncthreads();
  const __hip_bfloat16* p = (const __hip_bfloat16*)xyz;
  int local = 0;
  for (int i = threadIdx.x; i < n; i += 256){
    float v = __bfloat162float(p[i]);
    if (!(fabsf(v) < 1000.f)) local++;
  }
  atomicAdd(&cnt, local);
  __syncthreads();
  if (threadIdx.x == 0) *flag = (cnt < n/16) ? 1 : 0;   // 1 = bf16, 0 = fp32
}

__device__ __forceinline__ float rdval(const void* p, int i, int flag){
  return flag ? __bfloat162float(((const __hip_bfloat16*)p)[i]) : ((const float*)p)[i];
}

// ---------- fused small-input conversion + glob init ----------
__global__ void cvt_small_kernel(float* __restrict__ ws, const int* __restrict__ flag,
    const void* xyz, const void* s1, const void* b1, const void* s2, const void* b2,
    const void* s3, const void* b3, const void* s4, const void* b4,
    const void* sf, const void* bf, const void* se, const void* be,
    const void* sh1, const void* bh1, const void* sh2, const void* bh2, const void* bh3)
{
  int t = blockIdx.x*256 + threadIdx.x;
  int fl = *flag;
  if (t < 49152){ ws[O_XYZ + t] = rdval(xyz, t, fl); return; }
  t -= 49152;
  if (t < 4096){ ((unsigned*)(ws + O_GLOB))[t] = 0u; return; }
  t -= 4096;
  if (t < 64){ ws[O_S1+t] = rdval(s1,t,fl); return; }  t -= 64;
  if (t < 64){ ws[O_B1+t] = rdval(b1,t,fl); return; }  t -= 64;
  if (t < 64){ ws[O_S2+t] = rdval(s2,t,fl); return; }  t -= 64;
  if (t < 64){ ws[O_B2+t] = rdval(b2,t,fl); return; }  t -= 64;
  if (t < 128){ ws[O_S3+t] = rdval(s3,t,fl); return; } t -= 128;
  if (t < 128){ ws[O_B3+t] = rdval(b3,t,fl); return; } t -= 128;
  if (t < 256){ ws[O_S4+t] = rdval(s4,t,fl); return; } t -= 256;
  if (t < 256){ ws[O_B4+t] = rdval(b4,t,fl); return; } t -= 256;
  if (t < 512){ ws[O_SF+t] = rdval(sf,t,fl); return; } t -= 512;
  if (t < 512){ ws[O_BF+t] = rdval(bf,t,fl); return; } t -= 512;
  if (t < 1024){ ws[O_SE+t] = rdval(se,t,fl); return; } t -= 1024;
  if (t < 1024){ ws[O_BE+t] = rdval(be,t,fl); return; } t -= 1024;
  if (t < 256){ ws[O_SH1+t] = rdval(sh1,t,fl); return; } t -= 256;
  if (t < 256){ ws[O_BH1+t] = rdval(bh1,t,fl); return; } t -= 256;
  if (t < 256){ ws[O_SH2+t] = rdval(sh2,t,fl); return; } t -= 256;
  if (t < 256){ ws[O_BH2+t] = rdval(bh2,t,fl); return; } t -= 256;
  if (t < 50){ ws[O_BH3+t] = rdval(bh3,t,fl); return; }
}

// ---------- fused big-weight conversion -> bf16 hi/lo ----------
__global__ void cvt_w_kernel(float* __restrict__ ws, const int* __restrict__ flag,
    const void* wf, const void* we, const void* wh1, const void* wh2, const void* wh3)
{
  int t = blockIdx.x*256 + threadIdx.x;
  if (t >= WTOT) return;
  int fl = *flag;
  float v;
  if (t < (int)WOF_WE)        v = rdval(wf,  t, fl);
  else if (t < (int)WOF_WH1)  v = rdval(we,  t - WOF_WE, fl);
  else if (t < (int)WOF_WH2)  v = rdval(wh1, t - WOF_WH1, fl);
  else if (t < (int)WOF_WH3)  v = rdval(wh2, t - WOF_WH2, fl);
  else                        v = rdval(wh3, t - WOF_WH3, fl);
  __hip_bfloat16 h = __float2bfloat16(v);
  ((__hip_bfloat16*)(ws + O_WBH))[t] = h;
  ((__hip_bfloat16*)(ws + O_WBL))[t] = __float2bfloat16(v - __bfloat162float(h));
}

// ---------- edgeconv weight prep: wcat = [w_d ; w_x - w_d] -> bf16 h/l ----------
__global__ void prep_w_hl_kernel(float* __restrict__ ws, const int* __restrict__ flag,
                                 const void* __restrict__ w, int C, int O){
  int t = blockIdx.x*256 + threadIdx.x;
  if (t >= O*C) return;
  int fl = *flag;
  int o = t / C, c = t - o*C;
  float wd = rdval(w, o*2*C + c, fl);
  float wx = rdval(w, o*2*C + C + c, fl);
  float dx = wx - wd;
  __hip_bfloat16* Wh = (__hip_bfloat16*)(ws + O_WCATH);
  __hip_bfloat16* Wl = (__hip_bfloat16*)(ws + O_WCATL);
  __hip_bfloat16 h1 = __float2bfloat16(wd);
  Wh[o*C + c] = h1; Wl[o*C + c] = __float2bfloat16(wd - __bfloat162float(h1));
  __hip_bfloat16 h2 = __float2bfloat16(dx);
  Wh[(O+o)*C + c] = h2; Wl[(O+o)*C + c] = __float2bfloat16(dx - __bfloat162float(h2));
}

// layer-1 fp32 wcat [128][3]
__global__ void prep_w1_kernel(float* __restrict__ ws, const int* __restrict__ flag,
                               const void* __restrict__ w){
  int t = blockIdx.x*256 + threadIdx.x;
  if (t >= 64*3) return;
  int fl = *flag;
  int o = t / 3, c = t - o*3;
  float wd = rdval(w, o*6 + c, fl);
  float wx = rdval(w, o*6 + 3 + c, fl);
  ws[O_WCAT1 + o*3 + c] = wd;
  ws[O_WCAT1 + (64+o)*3 + c] = wx - wd;
}

// ---------- norms ----------
__global__ void norms_kernel(const float* __restrict__ x, int ld, int C, float* __restrict__ out){
  int t = blockIdx.x*256 + threadIdx.x;
  if (t >= Mm) return;
  const float* r = x + (size_t)t*ld;
  float s = 0.f;
  for (int c = 0; c < C; ++c){ float v = r[c]; s += v*v; }
  out[t] = s;
}
__global__ void norms_hl_kernel(const __hip_bfloat16* __restrict__ Xh, const __hip_bfloat16* __restrict__ Xl,
                                int ld, int C, float* __restrict__ out){
  int t = blockIdx.x*256 + threadIdx.x;
  if (t >= Mm) return;
  size_t base = (size_t)t*ld;
  float s = 0.f;
  for (int c = 0; c < C; ++c){
    float v = __bfloat162float(Xh[base+c]) + __bfloat162float(Xl[base+c]);
    s += v*v;
  }
  out[t] = s;
}

__device__ __forceinline__ unsigned fkey(float f){
  unsigned u = __float_as_uint(f);
  return (u & 0x80000000u) ? ~u : (u | 0x80000000u);
}
__device__ __forceinline__ float funkey(unsigned k){
  if (k == 0u) return -1e30f;
  unsigned u = (k & 0x80000000u) ? (k ^ 0x80000000u) : ~k;
  return __uint_as_float(u);
}

// distributed ascending top-20 across lanes 0..19 (1 u64/lane -> cannot spill).
// inserting a non-qualifying key (kk >= lane-19 value) is a natural no-op.
__device__ __forceinline__ u64 dlist_insert(u64 lst, u64 kk, int lane){
  u64 up = __shfl_up(lst, 1, 64);
  bool cs = lst > kk;
  bool cp = (lane > 0) && (up > kk);
  return cs ? (cp ? up : kk) : lst;
}

// full bitonic sort of 64 u64 keys across the wave (ascending by lane)
__device__ __forceinline__ u64 bitonic64_sort(u64 v, int lane){
  #pragma unroll
  for (int k = 2; k <= 64; k <<= 1){
    #pragma unroll
    for (int j = k >> 1; j >= 1; j >>= 1){
      u64 o = __shfl_xor(v, j, 64);
      bool up = ((lane & k) == 0);
      bool lower = ((lane & j) == 0);
      u64 mn = v < o ? v : o;
      u64 mx = v < o ? o : v;
      v = (up == lower) ? mn : mx;
    }
  }
  return v;
}

// ---------- MFMA KNN: wave owns 16 queries; distributed selection + bitonic init ----------
template<int C>
__global__ __launch_bounds__(256, 4) void knn_mfma_kernel(
    const __hip_bfloat16* __restrict__ Xh, const __hip_bfloat16* __restrict__ Xl, int lda,
    const float* __restrict__ n2,
    u64* __restrict__ kpart)
{
  constexpr int KS = C/32;
  __shared__ float dist[4][16*66];
  const int lane = threadIdx.x & 63;
  const int wv = threadIdx.x >> 6;
  const int b = blockIdx.z, bN = b*Nn;
  const int q0 = blockIdx.x*64 + wv*16;
  const int g = blockIdx.y;
  const int kq = (lane >> 4) * 8;
  float* dw = dist[wv];

  bf16x8 Ah[KS], Al[KS];
  {
    const size_t qrow = (size_t)(bN + q0 + (lane & 15))*lda;
    #pragma unroll
    for (int s = 0; s < KS; ++s){
      Ah[s] = *reinterpret_cast<const bf16x8*>(Xh + qrow + s*32 + kq);
      Al[s] = *reinterpret_cast<const bf16x8*>(Xl + qrow + s*32 + kq);
    }
  }

  auto compute_tiles = [&](int c0){
    #pragma unroll
    for (int tt = 0; tt < 4; ++tt){
      const int j0 = c0 + tt*16;
      const size_t crow = (size_t)(bN + j0 + (lane & 15))*lda;
      f32x4 acc = {0.f, 0.f, 0.f, 0.f};
      #pragma unroll
      for (int s = 0; s < KS; ++s){
        bf16x8 Bh = *reinterpret_cast<const bf16x8*>(Xh + crow + s*32 + kq);
        bf16x8 Bl = *reinterpret_cast<const bf16x8*>(Xl + crow + s*32 + kq);
        acc = __builtin_amdgcn_mfma_f32_16x16x32_bf16(Ah[s], Bh, acc, 0, 0, 0);
        acc = __builtin_amdgcn_mfma_f32_16x16x32_bf16(Ah[s], Bl, acc, 0, 0, 0);
        acc = __builtin_amdgcn_mfma_f32_16x16x32_bf16(Al[s], Bh, acc, 0, 0, 0);
      }
      float nj = n2[bN + j0 + (lane & 15)];
      const int rbase = (lane >> 4)*4;
      #pragma unroll
      for (int r = 0; r < 4; ++r)
        dw[(rbase + r)*66 + tt*16 + (lane & 15)] = nj - 2.f*acc[r];
    }
  };

  u64 lst[16];
  const int base = g*(Nn/Gg);

  // group 0: bitonic-sort init (no serial inserts)
  compute_tiles(base);
  #pragma unroll
  for (int q = 0; q < 16; ++q){
    float d = dw[q*66 + lane];
    u64 key = ((u64)fkey(d) << 32) | (unsigned)(base + lane);
    lst[q] = bitonic64_sort(key, lane);
  }

  for (int grp = 1; grp < (Nn/Gg)/64; ++grp){
    const int c0 = base + grp*64;
    compute_tiles(c0);
    #pragma unroll
    for (int q = 0; q < 16; ++q){
      float d = dw[q*66 + lane];
      u64 key = ((u64)fkey(d) << 32) | (unsigned)(c0 + lane);
      u64 thr = __shfl(lst[q], 19, 64);
      u64 bal = __ballot(key < thr);
      while (bal){
        int src = (int)__ffsll((unsigned long long)bal) - 1;
        bal &= bal - 1;
        u64 kk = __shfl(key, src, 64);
        lst[q] = dlist_insert(lst[q], kk, lane);
      }
    }
  }
  // output ascending lists
  #pragma unroll
  for (int q = 0; q < 16; ++q){
    if (lane < 20)
      kpart[((size_t)(bN + q0 + q)*Gg + g)*20 + lane] = lst[q];
  }
}

// ---------- KNN for C=3: one query per wave, distributed selection + bitonic init ----------
__global__ __launch_bounds__(256) void knn3_kernel(
    const float* __restrict__ x, const float* __restrict__ n2, int* __restrict__ idx)
{
  const int lane = threadIdx.x & 63;
  const int wv = threadIdx.x >> 6;
  const int q = blockIdx.x*4 + wv;
  const int b = q >> 12;
  const int bN = b*Nn;
  const int qi = q & (Nn-1);
  const float* qp = x + (size_t)(bN + qi)*3;
  float qx = qp[0], qy = qp[1], qz = qp[2];
  u64 lst;
  {
    const float* cp = x + (size_t)(bN + lane)*3;
    float d = n2[bN + lane] - 2.f*(qx*cp[0] + qy*cp[1] + qz*cp[2]);
    u64 key = ((u64)fkey(d) << 32) | (unsigned)lane;
    lst = bitonic64_sort(key, lane);
  }
  for (int s = 1; s < Nn/64; ++s){
    int j = s*64 + lane;
    const float* cp = x + (size_t)(bN + j)*3;
    float d = n2[bN + j] - 2.f*(qx*cp[0] + qy*cp[1] + qz*cp[2]);
    u64 key = ((u64)fkey(d) << 32) | (unsigned)j;
    u64 thr = __shfl(lst, 19, 64);
    u64 bal = __ballot(key < thr);
    while (bal){
      int src = (int)__ffsll((unsigned long long)bal) - 1;
      bal &= bal - 1;
      u64 kk = __shfl(key, src, 64);
      lst = dlist_insert(lst, kk, lane);
    }
  }
  if (lane < 20) idx[(size_t)q*Kk + lane] = (int)(lst & 0xffffffffu);
}

// ---------- final merge: Gg sorted ascending 20-lists -> top-20 ----------
__global__ __launch_bounds__(256, 4) void knn_final_merge_kernel(
    const u64* __restrict__ kpart, int* __restrict__ idx)
{
  int t = blockIdx.x*256 + threadIdx.x;
  if (t >= Mm) return;
  const u64* base = kpart + (size_t)t*Gg*20;
  KList kl; kl.init();
  for (int g = 0; g < Gg; ++g){
    const u64* lp = base + g*20;
    #pragma unroll 1
    for (int l = 0; l < 20; ++l){
      u64 key = lp[l];
      if (key >= kl.k0) break;
      kl.insert(key);
    }
  }
#define KOUTI(i) idx[(size_t)t*Kk + (19-(i))] = (int)(kl.k##i & 0xffffffffu);
  REP20(KOUTI)
#undef KOUTI
}

// ---------- gather-max epilogue: fp32 tb -> bf16 h/l activations ----------
__global__ void gathermax_kernel(const float* __restrict__ tb, const int* __restrict__ idx,
                                 const float* __restrict__ sv, const float* __restrict__ bv,
                                 int O, __hip_bfloat16* __restrict__ outh,
                                 __hip_bfloat16* __restrict__ outl, int ldo)
{
  int t = blockIdx.x*256 + threadIdx.x;
  int o = t % O;
  int m = t / O;
  int b = m / Nn;
  const int twoO = 2*O;
  const int* ip = idx + (size_t)m*Kk;
  float mx = -1e30f;
  for (int j = 0; j < Kk; ++j){
    int jj = ip[j] & (Nn-1);
    mx = fmaxf(mx, tb[(size_t)(b*Nn + jj)*twoO + o]);
  }
  float basev = tb[(size_t)m*twoO + O + o];
  float y = lrelu_f((mx + basev) * sv[o] + bv[o]);
  __hip_bfloat16 h = __float2bfloat16(y);
  outh[(size_t)m*ldo + o] = h;
  outl[(size_t)m*ldo + o] = __float2bfloat16(y - __bfloat162float(h));
}

// ---------- MFMA GEMM (LDS-staged): C[M,O] = (Ah+Al)[M,K] @ (Wh+Wl)[O,K]^T ----------
__global__ __launch_bounds__(256) void mfma_gemm_kernel(
    const __hip_bfloat16* __restrict__ Ah, const __hip_bfloat16* __restrict__ Al, int lda,
    const __hip_bfloat16* __restrict__ Wh, const __hip_bfloat16* __restrict__ Wl, int ldw,
    float* __restrict__ Cf, __hip_bfloat16* __restrict__ Ch, __hip_bfloat16* __restrict__ Cl, int ldc,
    int K, int O,
    const float* __restrict__ scale, const float* __restrict__ bias,
    const float* __restrict__ addvec, int lrelu_flag,
    unsigned* __restrict__ pool)
{
  constexpr int LDK = 40;
  __shared__ __align__(16) __hip_bfloat16 AsH[128*LDK];
  __shared__ __align__(16) __hip_bfloat16 AsL[128*LDK];
  __shared__ __align__(16) __hip_bfloat16 BsH[128*LDK];
  __shared__ __align__(16) __hip_bfloat16 BsL[128*LDK];
  __shared__ float redp[2][128];
  const int tid = threadIdx.x;
  const int lane = tid & 63, w = tid >> 6;
  const int o0 = blockIdx.x*128, m0 = blockIdx.y*128;
  const int wr = (w >> 1)*64, wc = (w & 1)*64;
  const int kq = (lane >> 4)*8;
  const int fr = lane & 15;
  f32x4 acc[4][4] = {};

  for (int k0 = 0; k0 < K; k0 += 32){
    __syncthreads();
    #pragma unroll
    for (int j = 0; j < 2; ++j){
      int chunk = tid + j*256;
      int r = chunk >> 2, k8 = (chunk & 3)*8;
      size_t ga = (size_t)(m0 + r)*lda + k0 + k8;
      int oo = o0 + r; if (oo >= O) oo = O - 1;
      size_t gb = (size_t)oo*ldw + k0 + k8;
      int ls = r*LDK + k8;
      *reinterpret_cast<bf16x8*>(&AsH[ls]) = *reinterpret_cast<const bf16x8*>(Ah + ga);
      *reinterpret_cast<bf16x8*>(&AsL[ls]) = *reinterpret_cast<const bf16x8*>(Al + ga);
      *reinterpret_cast<bf16x8*>(&BsH[ls]) = *reinterpret_cast<const bf16x8*>(Wh + gb);
      *reinterpret_cast<bf16x8*>(&BsL[ls]) = *reinterpret_cast<const bf16x8*>(Wl + gb);
    }
    __syncthreads();
    bf16x8 ah[4], al[4];
    #pragma unroll
    for (int mi = 0; mi < 4; ++mi){
      int ls = (wr + mi*16 + fr)*LDK + kq;
      ah[mi] = *reinterpret_cast<const bf16x8*>(&AsH[ls]);
      al[mi] = *reinterpret_cast<const bf16x8*>(&AsL[ls]);
    }
    #pragma unroll
    for (int ni = 0; ni < 4; ++ni){
      int ls = (wc + ni*16 + fr)*LDK + kq;
      bf16x8 bh = *reinterpret_cast<const bf16x8*>(&BsH[ls]);
      bf16x8 bl = *reinterpret_cast<const bf16x8*>(&BsL[ls]);
      #pragma unroll
      for (int mi = 0; mi < 4; ++mi){
        acc[mi][ni] = __builtin_amdgcn_mfma_f32_16x16x32_bf16(ah[mi], bh, acc[mi][ni], 0, 0, 0);
        acc[mi][ni] = __builtin_amdgcn_mfma_f32_16x16x32_bf16(ah[mi], bl, acc[mi][ni], 0, 0, 0);
        acc[mi][ni] = __builtin_amdgcn_mfma_f32_16x16x32_bf16(al[mi], bh, acc[mi][ni], 0, 0, 0);
      }
    }
  }
  const int b = m0 / Nn;
  if (pool){
    #pragma unroll
    for (int ni = 0; ni < 4; ++ni){
      int o = o0 + wc + ni*16 + fr;
      float sc_ = scale[o], bi_ = bias[o];
      float m = -1e30f;
      #pragma unroll
      for (int mi = 0; mi < 4; ++mi)
        #pragma unroll
        for (int r = 0; r < 4; ++r)
          m = fmaxf(m, lrelu_f(acc[mi][ni][r]*sc_ + bi_));
      m = fmaxf(m, __shfl_xor(m, 16, 64));
      m = fmaxf(m, __shfl_xor(m, 32, 64));
      if ((lane >> 4) == 0) redp[w >> 1][wc + ni*16 + fr] = m;
    }
    __syncthreads();
    if (tid < 128){
      float m = fmaxf(redp[0][tid], redp[1][tid]);
      atomicMax(&pool[b*O + o0 + tid], fkey(m));
    }
    return;
  }
  #pragma unroll
  for (int ni = 0; ni < 4; ++ni){
    int o = o0 + wc + ni*16 + fr;
    if (o >= O) continue;
    float sc_ = scale ? scale[o] : 1.f;
    float bi_ = bias ? bias[o] : 0.f;
    float av  = addvec ? addvec[b*O + o] : 0.f;
    #pragma unroll
    for (int mi = 0; mi < 4; ++mi){
      #pragma unroll
      for (int r = 0; r < 4; ++r){
        int m = m0 + wr + mi*16 + (lane >> 4)*4 + r;
        float y = acc[mi][ni][r] + av;
        if (scale) y = y*sc_ + bi_;
        else       y = y + bi_;
        if (lrelu_flag) y = lrelu_f(y);
        if (Ch){
          __hip_bfloat16 h = __float2bfloat16(y);
          Ch[(size_t)m*ldc + o] = h;
          Cl[(size_t)m*ldc + o] = __float2bfloat16(y - __bfloat162float(h));
        } else {
          Cf[(size_t)m*ldc + o] = y;
        }
      }
    }
  }
}

// ---------- fp32 GEMM (layer-1 tb only, K=3) ----------
__global__ __launch_bounds__(256) void gemm_kernel(
    const float* __restrict__ A, int lda,
    const float* __restrict__ W, int ldw,
    float* __restrict__ Cf, int ldc, int K, int O)
{
  const int tid = threadIdx.x;
  const int tx = tid & 15, ty = tid >> 4;
  const int m0 = blockIdx.y * 64;
  const int o0 = blockIdx.x * 64;
  __shared__ __align__(16) float As[16*68];
  __shared__ __align__(16) float Ws[16*68];
  float acc[4][4] = {};
  for (int k0 = 0; k0 < K; k0 += 16){
    __syncthreads();
    #pragma unroll
    for (int r = 0; r < 4; ++r){
      int e = tid + r*256;
      int k = e & 15, mi = e >> 4;
      int kk = k0 + k;
      float v = 0.f, wv = 0.f;
      if (kk < K) v = A[(size_t)(m0+mi)*lda + kk];
      int oo = o0 + mi;
      if (kk < K && oo < O) wv = W[(size_t)oo*ldw + kk];
      As[k*68 + mi] = v;
      Ws[k*68 + mi] = wv;
    }
    __syncthreads();
    #pragma unroll
    for (int kk = 0; kk < 16; ++kk){
      float4 av = *reinterpret_cast<const float4*>(&As[kk*68 + ty*4]);
      float4 wv = *reinterpret_cast<const float4*>(&Ws[kk*68 + tx*4]);
      float a4[4] = {av.x, av.y, av.z, av.w};
      float w4[4] = {wv.x, wv.y, wv.z, wv.w};
      #pragma unroll
      for (int i = 0; i < 4; ++i)
        #pragma unroll
        for (int j = 0; j < 4; ++j)
          acc[i][j] += a4[i]*w4[j];
    }
  }
  #pragma unroll
  for (int i = 0; i < 4; ++i){
    int m = m0 + ty*4 + i;
    #pragma unroll
    for (int j = 0; j < 4; ++j){
      int o = o0 + tx*4 + j;
      if (o >= O) continue;
      Cf[(size_t)m*ldc + o] = acc[i][j];
    }
  }
}

// gvec[b,o2] = sum_c wh1[o2, 512+c] * glob[b,c]
__global__ void gvec_kernel(const __hip_bfloat16* __restrict__ Wh, const __hip_bfloat16* __restrict__ Wl,
                            const unsigned* __restrict__ glob, float* __restrict__ gv){
  int lane = threadIdx.x & 63, w = threadIdx.x >> 6;
  int o2 = blockIdx.x*4 + w;
  int b = blockIdx.y;
  size_t base = (size_t)o2*1536 + 512;
  float s = 0.f;
  for (int c = lane; c < 1024; c += 64){
    float wv = __bfloat162float(Wh[base+c]) + __bfloat162float(Wl[base+c]);
    s += wv * funkey(glob[b*1024 + c]);
  }
  #pragma unroll
  for (int off = 32; off >= 1; off >>= 1) s += __shfl_xor(s, off, 64);
  if (lane == 0) gv[b*256 + o2] = s;
}

// ---------- flag-gated output store ----------
__global__ void store_out_kernel(const float* __restrict__ src, const int* __restrict__ flag,
                                 void* __restrict__ dst, int n){
  int t = blockIdx.x*256 + threadIdx.x;
  if (t >= n) return;
  float v = src[t];
  if (*flag) ((__hip_bfloat16*)dst)[t] = __float2bfloat16(v);
  else       ((float*)dst)[t] = v;
}

extern "C" void kernel_launch(void* const* d_in, const int* in_sizes, int n_in,
                              void* d_out, int out_size, void* d_ws, size_t ws_size,
                              hipStream_t stream) {
  (void)in_sizes; (void)n_in; (void)out_size; (void)ws_size;
  float* ws = (float*)d_ws;
  int* dflag = (int*)(ws + O_DFLAG);
  float* xyzf = ws + O_XYZ;
  float* nrm  = ws + O_NRM;
  int*   idx  = (int*)(ws + O_IDX);
  unsigned* glob = (unsigned*)(ws + O_GLOB);
  float* gv = ws + O_GV;
  __hip_bfloat16* WBH = (__hip_bfloat16*)(ws + O_WBH);
  __hip_bfloat16* WBL = (__hip_bfloat16*)(ws + O_WBL);
  __hip_bfloat16* WCH = (__hip_bfloat16*)(ws + O_WCATH);
  __hip_bfloat16* WCL = (__hip_bfloat16*)(ws + O_WCATL);
  __hip_bfloat16* XCH = (__hip_bfloat16*)(ws + O_XCATH);
  __hip_bfloat16* XCL = (__hip_bfloat16*)(ws + O_XCATL);
  float* regB = ws + O_REGB;
  u64*   kpart = (u64*)regB;
  float* tb    = regB;
  __hip_bfloat16* XLH = (__hip_bfloat16*)regB;
  __hip_bfloat16* XLL = (__hip_bfloat16*)(regB + 4194304);
  float* logitsF = regB;
  __hip_bfloat16* H1H = (__hip_bfloat16*)(ws + O_H1H);
  __hip_bfloat16* H1L = (__hip_bfloat16*)(ws + O_H1L);
  __hip_bfloat16* H2H = (__hip_bfloat16*)(ws + O_H2H);
  __hip_bfloat16* H2L = (__hip_bfloat16*)(ws + O_H2L);

  // ---- detect + fused conversions ----
  detect_kernel<<<1, 256, 0, stream>>>(d_in[0], Mm*3, dflag);
  cvt_small_kernel<<<(49152+4096+5200+255)/256, 256, 0, stream>>>(ws, dflag,
      d_in[0], d_in[3], d_in[4], d_in[6], d_in[7], d_in[9], d_in[10], d_in[12], d_in[13],
      d_in[15], d_in[16], d_in[18], d_in[19], d_in[21], d_in[22], d_in[24], d_in[25], d_in[27]);
  cvt_w_kernel<<<(WTOT+255)/256, 256, 0, stream>>>(ws, dflag,
      d_in[14], d_in[17], d_in[20], d_in[23], d_in[26]);

  auto mgemm = [&](const __hip_bfloat16* Ah, const __hip_bfloat16* Al, int lda,
                   const __hip_bfloat16* Wh, const __hip_bfloat16* Wl, int ldw,
                   float* Cf, __hip_bfloat16* Ch, __hip_bfloat16* Cl, int ldc,
                   int K, int O, const float* sc, const float* bi, const float* av,
                   int lr, unsigned* pool){
    dim3 g((O+127)/128, Mm/128);
    mfma_gemm_kernel<<<g, 256, 0, stream>>>(Ah, Al, lda, Wh, Wl, ldw, Cf, Ch, Cl, ldc,
                                            K, O, sc, bi, av, lr, pool);
  };

  // ---- edgeconv layer 1 (C=3) ----
  norms_kernel<<<Mm/256, 256, 0, stream>>>(xyzf, 3, 3, nrm);
  knn3_kernel<<<Mm/4, 256, 0, stream>>>(xyzf, nrm, idx);
  prep_w1_kernel<<<1, 256, 0, stream>>>(ws, dflag, d_in[2]);
  gemm_kernel<<<dim3(2, Mm/64), 256, 0, stream>>>(xyzf, 3, ws + O_WCAT1, 3, tb, 128, 3, 128);
  gathermax_kernel<<<((size_t)Mm*64)/256, 256, 0, stream>>>(
      tb, idx, ws+O_S1, ws+O_B1, 64, XCH + 0, XCL + 0, 512);

  // ---- edgeconv layers 2-4 (MFMA path) ----
  struct LayerDef { int coff; int C; int O; size_t so, bo; int win; };
  LayerDef L[3] = {
    {0,   64, 64,  O_S2, O_B2, 5},
    {64,  64, 128, O_S3, O_B3, 8},
    {128, 128, 256, O_S4, O_B4, 11},
  };
  for (int li = 0; li < 3; ++li){
    int C = L[li].C, O = L[li].O, coff = L[li].coff;
    norms_hl_kernel<<<Mm/256, 256, 0, stream>>>(XCH + coff, XCL + coff, 512, C, nrm);
    if (C == 64)
      knn_mfma_kernel<64><<<dim3(Nn/64, Gg, Bb), 256, 0, stream>>>(XCH + coff, XCL + coff, 512, nrm, kpart);
    else
      knn_mfma_kernel<128><<<dim3(Nn/64, Gg, Bb), 256, 0, stream>>>(XCH + coff, XCL + coff, 512, nrm, kpart);
    knn_final_merge_kernel<<<Mm/256, 256, 0, stream>>>(kpart, idx);
    prep_w_hl_kernel<<<(O*C+255)/256, 256, 0, stream>>>(ws, dflag, d_in[L[li].win], C, O);
    mgemm(XCH + coff, XCL + coff, 512, WCH, WCL, C, tb, nullptr, nullptr, 2*O, C, 2*O,
          nullptr, nullptr, nullptr, 0, nullptr);
    gathermax_kernel<<<((size_t)Mm*O)/256, 256, 0, stream>>>(
        tb, idx, ws + L[li].so, ws + L[li].bo, O, XCH + coff + C, XCL + coff + C, 512);
  }

  // ---- chain ----
  mgemm(XCH, XCL, 512, WBH + WOF_WF, WBL + WOF_WF, 512, nullptr, XLH, XLL, 512,
        512, 512, ws+O_SF, ws+O_BF, nullptr, 1, nullptr);
  mgemm(XLH, XLL, 512, WBH + WOF_WE, WBL + WOF_WE, 512, nullptr, nullptr, nullptr, 0,
        512, 1024, ws+O_SE, ws+O_BE, nullptr, 1, glob);
  gvec_kernel<<<dim3(64, Bb), 256, 0, stream>>>(WBH + WOF_WH1, WBL + WOF_WH1, glob, gv);
  mgemm(XLH, XLL, 512, WBH + WOF_WH1, WBL + WOF_WH1, 1536, nullptr, H1H, H1L, 256,
        512, 256, ws+O_SH1, ws+O_BH1, gv, 1, nullptr);
  mgemm(H1H, H1L, 256, WBH + WOF_WH2, WBL + WOF_WH2, 256, nullptr, H2H, H2L, 256,
        256, 256, ws+O_SH2, ws+O_BH2, nullptr, 1, nullptr);
  mgemm(H2H, H2L, 256, WBH + WOF_WH3, WBL + WOF_WH3, 256, logitsF, nullptr, nullptr, 50,
        256, 50, nullptr, ws+O_BH3, nullptr, 0, nullptr);
  store_out_kernel<<<((size_t)Mm*50 + 255)/256, 256, 0, stream>>>(logitsF, dflag, d_out, Mm*50);
}